// Round 1
// baseline (1127.525 us; speedup 1.0000x reference)
//
#include <hip/hip_runtime.h>

typedef unsigned short u16;
typedef unsigned int   u32;
typedef __bf16 bf16x8 __attribute__((ext_vector_type(8)));
typedef float  f32x4  __attribute__((ext_vector_type(4)));
typedef u32    u32x4  __attribute__((ext_vector_type(4)));
typedef u16    u16x4  __attribute__((ext_vector_type(4)));

#define V_N   6890
#define V_PAD 6912

__device__ __forceinline__ float bf2f(u32 h) {
  union { u32 u; float f; } c; c.u = h << 16; return c.f;
}
__device__ __forceinline__ u16 f2bf(float f) {
  union { float f; u32 u; } c; c.f = f;
  return (u16)((c.u + 0x7fffu + ((c.u >> 16) & 1u)) >> 16);
}
__device__ __forceinline__ void gload_lds16(const void* g, void* l) {
  __builtin_amdgcn_global_load_lds((const __attribute__((address_space(1))) void*)g,
                                   (__attribute__((address_space(3))) void*)l, 16, 0, 0);
}

// ---- f32 -> bf16 (vec4) ----
__global__ void cvt_kernel(const float* __restrict__ in, u16* __restrict__ out, int total4) {
  int g = blockIdx.x * 256 + threadIdx.x;
  if (g >= total4) return;
  f32x4 v = *(const f32x4*)(in + (size_t)g * 4);
  u16x4 o; o.x = f2bf(v.x); o.y = f2bf(v.y); o.z = f2bf(v.z); o.w = f2bf(v.w);
  *(u16x4*)(out + (size_t)g * 4) = o;
}

// ---- build rotated templates, bf16, B^T layout: Trot[(o*Tn+t)][ (r*8+a)*Cc + c ] = T[t][r][(a-o)&7][c] ----
__global__ void trot_kernel(const float* __restrict__ T, u16* __restrict__ out,
                            int Tn, int Cc, int C4, int total) {
  int g = blockIdx.x * 256 + threadIdx.x;
  if (g >= total) return;
  int c4 = g % C4; int q = g / C4;
  int a = q & 7; q >>= 3;
  int r = q % 5; q /= 5;
  int t = q % Tn; int o = q / Tn;
  f32x4 s = *(const f32x4*)(T + (size_t)((t * 5 + r) * 8 + ((a - o + 8) & 7)) * Cc + c4 * 4);
  u16x4 d; d.x = f2bf(s.x); d.y = f2bf(s.y); d.z = f2bf(s.z); d.w = f2bf(s.w);
  *(u16x4*)(out + ((size_t)(o * Tn + t) * 40 + (r * 8 + a)) * Cc + c4 * 4) = d;
}

// ---- barycentric gather+interp: out[vr][ (r*8+a)*Cc + c ] bf16, vec8 per thread ----
__global__ void interp_kernel(const u16* __restrict__ sig, int Cc, int C8,
                              const int* __restrict__ idx, const float* __restrict__ w,
                              u16* __restrict__ out, int v0, int Kl, int total) {
  int g = blockIdx.x * 256 + threadIdx.x;
  if (g >= total) return;
  int q = g / C8, c8 = g - q * C8;
  int vr = q / 40, ra = q - vr * 40;
  size_t ib = ((size_t)(v0 + vr) * 40 + ra) * 3;
  int i0 = idx[ib], i1 = idx[ib + 1], i2 = idx[ib + 2];
  float w0 = w[ib], w1 = w[ib + 1], w2 = w[ib + 2];
  u32x4 s0 = *(const u32x4*)(sig + (size_t)i0 * Cc + c8 * 8);
  u32x4 s1 = *(const u32x4*)(sig + (size_t)i1 * Cc + c8 * 8);
  u32x4 s2 = *(const u32x4*)(sig + (size_t)i2 * Cc + c8 * 8);
  u32x4 o;
#pragma unroll
  for (int j = 0; j < 4; ++j) {
    float lo = w0 * bf2f(s0[j] & 0xffffu) + w1 * bf2f(s1[j] & 0xffffu) + w2 * bf2f(s2[j] & 0xffffu);
    float hi = w0 * bf2f(s0[j] >> 16)     + w1 * bf2f(s1[j] >> 16)     + w2 * bf2f(s2[j] >> 16);
    o[j] = (u32)f2bf(lo) | ((u32)f2bf(hi) << 16);
  }
  *(u32x4*)(out + (size_t)vr * Kl + ra * Cc + c8 * 8) = o;
}

// ---- relu(+bias) + angular max over 8 rotations; optional split-bf16 (hi|lo) output ----
__global__ void amp_kernel(const float* __restrict__ Cin, const float* __restrict__ bias,
                           u16* __restrict__ out, int Tn, int ldo, int split, int total) {
  int g = blockIdx.x * 256 + threadIdx.x;
  if (g >= total) return;
  int t = g % Tn, v = g / Tn;
  const float* row = Cin + (size_t)v * (8 * Tn) + t;
  float b = bias[t];
  float m = row[0] + b;
#pragma unroll
  for (int o = 1; o < 8; ++o) m = fmaxf(m, row[(size_t)o * Tn] + b);
  m = fmaxf(m, 0.f);
  u16 hi = f2bf(m);
  out[(size_t)v * ldo + t] = hi;
  if (split) out[(size_t)v * ldo + Tn + t] = f2bf(m - bf2f(hi));
}

// ---- Wd [128][V] f32 -> WdT split-bf16 [V_PAD][256] (hi | lo along k) ----
__global__ void wdt_kernel(const float* __restrict__ Wd, u16* __restrict__ out, int total) {
  int g = blockIdx.x * 256 + threadIdx.x;
  if (g >= total) return;
  int k = g & 127, n = g >> 7;
  float v = (n < V_N) ? Wd[(size_t)k * V_N + n] : 0.f;
  u16 hi = f2bf(v);
  out[(size_t)n * 256 + k] = hi;
  out[(size_t)n * 256 + 128 + k] = f2bf(v - bf2f(hi));
}

// ---- bf16 GEMM: C[m][n] = sum_k A[m][k] * B[n][k]  (B is B^T layout), f32 out, optional bias ----
// 128x128 tile, BK=64, 4 waves (2x2), 16x16x32 MFMA, global_load_lds width 16.
__global__ __launch_bounds__(256) void gemm_bt(
    const u16* __restrict__ A, int lda,
    const u16* __restrict__ B, int ldb,
    float* __restrict__ C, int ldc,
    const float* __restrict__ bias,
    int M, int N, int K) {
  __shared__ __align__(16) u16 lA[128 * 64];
  __shared__ __align__(16) u16 lB[128 * 64];
  const int tid = threadIdx.x;
  const int w = tid >> 6, l = tid & 63;
  const int tm = blockIdx.y, tn = blockIdx.x;
  const u16* Ab = A + (size_t)tm * 128 * lda;
  const u16* Bb = B + (size_t)tn * 128 * ldb;
  f32x4 acc[4][4];
#pragma unroll
  for (int i = 0; i < 4; ++i)
#pragma unroll
    for (int j = 0; j < 4; ++j) acc[i][j] = (f32x4){0.f, 0.f, 0.f, 0.f};
  const int wm = w >> 1, wn = w & 1;
  const int arow = wm * 64 + (l & 15);
  const int brow = wn * 64 + (l & 15);
  const int kcol = (l >> 4) * 8;
  const int srow = w * 8 + (l >> 3);
  const int scol = (l & 7) * 8;
  for (int k0 = 0; k0 < K; k0 += 64) {
#pragma unroll
    for (int i = 0; i < 4; ++i) {
      gload_lds16(Ab + (size_t)(srow + i * 32) * lda + k0 + scol, &lA[(i * 256 + w * 64) * 8]);
      gload_lds16(Bb + (size_t)(srow + i * 32) * ldb + k0 + scol, &lB[(i * 256 + w * 64) * 8]);
    }
    __syncthreads();
#pragma unroll
    for (int kk = 0; kk < 2; ++kk) {
      bf16x8 af[4], bb[4];
#pragma unroll
      for (int mi = 0; mi < 4; ++mi)
        af[mi] = *(const bf16x8*)&lA[(arow + mi * 16) * 64 + kk * 32 + kcol];
#pragma unroll
      for (int ni = 0; ni < 4; ++ni)
        bb[ni] = *(const bf16x8*)&lB[(brow + ni * 16) * 64 + kk * 32 + kcol];
#pragma unroll
      for (int mi = 0; mi < 4; ++mi)
#pragma unroll
        for (int ni = 0; ni < 4; ++ni)
          acc[mi][ni] = __builtin_amdgcn_mfma_f32_16x16x32_bf16(af[mi], bb[ni], acc[mi][ni], 0, 0, 0);
    }
    __syncthreads();
  }
  const int crow = wm * 64 + ((l >> 4) << 2);
  const int ccol = wn * 64 + (l & 15);
#pragma unroll
  for (int mi = 0; mi < 4; ++mi) {
#pragma unroll
    for (int j = 0; j < 4; ++j) {
      int grow = tm * 128 + crow + mi * 16 + j;
      if (grow < M) {
#pragma unroll
        for (int ni = 0; ni < 4; ++ni) {
          int gcol = tn * 128 + ccol + ni * 16;
          if (gcol < N) {
            float v = acc[mi][ni][j];
            if (bias) v += bias[gcol];
            C[(size_t)grow * ldc + gcol] = v;
          }
        }
      }
    }
  }
}

static inline int imin(int a, int b) { return a < b ? a : b; }

extern "C" void kernel_launch(void* const* d_in, const int* in_sizes, int n_in,
                              void* d_out, int out_size, void* d_ws, size_t ws_size,
                              hipStream_t stream) {
  const float* signal = (const float*)d_in[0];
  const int*   bc_idx = (const int*)d_in[1];
  const float* bc_w   = (const float*)d_in[2];
  const float* tmpl[3] = { (const float*)d_in[3], (const float*)d_in[5], (const float*)d_in[7] };
  const float* tb[3]   = { (const float*)d_in[4], (const float*)d_in[6], (const float*)d_in[8] };
  const float* Wd = (const float*)d_in[9];
  const float* bd = (const float*)d_in[10];
  float* outp = (float*)d_out;

  char* ws = (char*)d_ws;
  size_t off = 0;
  auto alloc = [&](size_t b) -> void* {
    size_t o = (off + 255) & ~(size_t)255; off = o + b; return (void*)(ws + o);
  };
  u16* sigbf = (u16*)alloc((size_t)V_N * 544 * 2);
  u16* outL0 = (u16*)alloc((size_t)V_N * 96 * 2);
  u16* outL1 = (u16*)alloc((size_t)V_N * 128 * 2);
  u16* outL2 = (u16*)alloc((size_t)V_PAD * 256 * 2);   // split hi|lo, padded rows for dense GEMM
  u16* trot  = (u16*)alloc((size_t)768 * 21760 * 2);   // max over layers; reused for WdT
  float* gemmC = (float*)alloc((size_t)V_N * 1024 * 4);
  size_t o2 = (off + 255) & ~(size_t)255;
  u16* interp = (u16*)(ws + o2);
  size_t interpElems = (ws_size > o2) ? (ws_size - o2) / 2 : 0;

  { // signal -> bf16
    int total4 = V_N * 544 / 4;
    cvt_kernel<<<dim3((total4 + 255) / 256), dim3(256), 0, stream>>>(signal, sigbf, total4);
  }

  const int TnA[3] = {96, 128, 128}, CcA[3] = {544, 96, 128};
  u16* outs[3] = { outL0, outL1, outL2 };
  const u16* cursig = sigbf;
  for (int L = 0; L < 3; ++L) {
    const int Tn = TnA[L], Cc = CcA[L];
    const int K = 40 * Cc, N = 8 * Tn, C8 = Cc / 8, C4 = Cc / 4;
    { int total = N * 40 * C4;
      trot_kernel<<<dim3((total + 255) / 256), dim3(256), 0, stream>>>(tmpl[L], trot, Tn, Cc, C4, total); }
    long crl = (long)(interpElems / (size_t)K) & ~(long)127;
    int cr = (crl > (long)V_PAD) ? V_PAD : (int)crl;
    if (cr < 128) cr = 128;  // requires ws_size >= fixed(+~74MB) + 5.6MB
    for (int v0 = 0; v0 < V_PAD; v0 += cr) {
      int rows = imin(cr, V_PAD - v0);
      int nv = imin(rows, V_N - v0);
      { int total = nv * 40 * C8;
        interp_kernel<<<dim3((total + 255) / 256), dim3(256), 0, stream>>>(
            cursig, Cc, C8, bc_idx, bc_w, interp, v0, K, total); }
      gemm_bt<<<dim3(N / 128, rows / 128), dim3(256), 0, stream>>>(
          interp, K, trot, K, gemmC + (size_t)v0 * N, N, nullptr, nv, N, K);
    }
    { int total = V_N * Tn;
      int ldo = (L == 2) ? 256 : ((L == 0) ? 96 : 128);
      amp_kernel<<<dim3((total + 255) / 256), dim3(256), 0, stream>>>(
          gemmC, tb[L], outs[L], Tn, ldo, (L == 2) ? 1 : 0, total); }
    cursig = outs[L];
  }

  { int total = V_PAD * 128;
    wdt_kernel<<<dim3((total + 255) / 256), dim3(256), 0, stream>>>(Wd, trot, total); }
  gemm_bt<<<dim3(V_PAD / 128, V_PAD / 128), dim3(256), 0, stream>>>(
      outL2, 256, trot, 256, outp, V_N, bd, V_N, V_N, 256);
}

// Round 2
// 945.011 us; speedup vs baseline: 1.1931x; 1.1931x over previous
//
#include <hip/hip_runtime.h>

typedef unsigned short u16;
typedef unsigned int   u32;
typedef __bf16 bf16x8 __attribute__((ext_vector_type(8)));
typedef float  f32x4  __attribute__((ext_vector_type(4)));
typedef u32    u32x4  __attribute__((ext_vector_type(4)));
typedef u16    u16x4  __attribute__((ext_vector_type(4)));

#define V_N   6890
#define V_PAD 6912

__device__ __forceinline__ float bf2f(u32 h) {
  union { u32 u; float f; } c; c.u = h << 16; return c.f;
}
__device__ __forceinline__ u16 f2bf(float f) {
  union { float f; u32 u; } c; c.f = f;
  return (u16)((c.u + 0x7fffu + ((c.u >> 16) & 1u)) >> 16);
}
__device__ __forceinline__ void gload_lds16(const void* g, void* l) {
  __builtin_amdgcn_global_load_lds((const __attribute__((address_space(1))) void*)g,
                                   (__attribute__((address_space(3))) void*)l, 16, 0, 0);
}

// ---- f32 -> bf16 (vec4) ----
__global__ void cvt_kernel(const float* __restrict__ in, u16* __restrict__ out, int total4) {
  int g = blockIdx.x * 256 + threadIdx.x;
  if (g >= total4) return;
  f32x4 v = *(const f32x4*)(in + (size_t)g * 4);
  u16x4 o; o.x = f2bf(v.x); o.y = f2bf(v.y); o.z = f2bf(v.z); o.w = f2bf(v.w);
  *(u16x4*)(out + (size_t)g * 4) = o;
}

// ---- build rotated templates, bf16, B^T layout ----
__global__ void trot_kernel(const float* __restrict__ T, u16* __restrict__ out,
                            int Tn, int Cc, int C4, int total) {
  int g = blockIdx.x * 256 + threadIdx.x;
  if (g >= total) return;
  int c4 = g % C4; int q = g / C4;
  int a = q & 7; q >>= 3;
  int r = q % 5; q /= 5;
  int t = q % Tn; int o = q / Tn;
  f32x4 s = *(const f32x4*)(T + (size_t)((t * 5 + r) * 8 + ((a - o + 8) & 7)) * Cc + c4 * 4);
  u16x4 d; d.x = f2bf(s.x); d.y = f2bf(s.y); d.z = f2bf(s.z); d.w = f2bf(s.w);
  *(u16x4*)(out + ((size_t)(o * Tn + t) * 40 + (r * 8 + a)) * Cc + c4 * 4) = d;
}

// ---- barycentric gather+interp ----
__global__ void interp_kernel(const u16* __restrict__ sig, int Cc, int C8,
                              const int* __restrict__ idx, const float* __restrict__ w,
                              u16* __restrict__ out, int v0, int Kl, int total) {
  int g = blockIdx.x * 256 + threadIdx.x;
  if (g >= total) return;
  int q = g / C8, c8 = g - q * C8;
  int vr = q / 40, ra = q - vr * 40;
  size_t ib = ((size_t)(v0 + vr) * 40 + ra) * 3;
  int i0 = idx[ib], i1 = idx[ib + 1], i2 = idx[ib + 2];
  float w0 = w[ib], w1 = w[ib + 1], w2 = w[ib + 2];
  u32x4 s0 = *(const u32x4*)(sig + (size_t)i0 * Cc + c8 * 8);
  u32x4 s1 = *(const u32x4*)(sig + (size_t)i1 * Cc + c8 * 8);
  u32x4 s2 = *(const u32x4*)(sig + (size_t)i2 * Cc + c8 * 8);
  u32x4 o;
#pragma unroll
  for (int j = 0; j < 4; ++j) {
    float lo = w0 * bf2f(s0[j] & 0xffffu) + w1 * bf2f(s1[j] & 0xffffu) + w2 * bf2f(s2[j] & 0xffffu);
    float hi = w0 * bf2f(s0[j] >> 16)     + w1 * bf2f(s1[j] >> 16)     + w2 * bf2f(s2[j] >> 16);
    o[j] = (u32)f2bf(lo) | ((u32)f2bf(hi) << 16);
  }
  *(u32x4*)(out + (size_t)vr * Kl + ra * Cc + c8 * 8) = o;
}

// ---- split-K reduce + relu(+bias) + angular max; optional split-bf16 (hi|lo) output ----
__global__ void amp_kernel(const float* __restrict__ Cin, size_t cstride, int nsplit,
                           const float* __restrict__ bias, u16* __restrict__ out,
                           int Tn, int ldo, int split, int total) {
  int g = blockIdx.x * 256 + threadIdx.x;
  if (g >= total) return;
  int t = g % Tn, v = g / Tn;
  const float* row = Cin + (size_t)v * (8 * Tn) + t;
  float acc[8];
#pragma unroll
  for (int o = 0; o < 8; ++o) acc[o] = row[(size_t)o * Tn];
  for (int s = 1; s < nsplit; ++s) {
    row += cstride;
#pragma unroll
    for (int o = 0; o < 8; ++o) acc[o] += row[(size_t)o * Tn];
  }
  float b = bias[t];
  float m = acc[0] + b;
#pragma unroll
  for (int o = 1; o < 8; ++o) m = fmaxf(m, acc[o] + b);
  m = fmaxf(m, 0.f);
  u16 hi = f2bf(m);
  out[(size_t)v * ldo + t] = hi;
  if (split) out[(size_t)v * ldo + Tn + t] = f2bf(m - bf2f(hi));
}

// ---- Wd [128][V] f32 -> WdT split-bf16 [V_PAD][256] (hi | lo along k) ----
__global__ void wdt_kernel(const float* __restrict__ Wd, u16* __restrict__ out, int total) {
  int g = blockIdx.x * 256 + threadIdx.x;
  if (g >= total) return;
  int k = g & 127, n = g >> 7;
  float v = (n < V_N) ? Wd[(size_t)k * V_N + n] : 0.f;
  u16 hi = f2bf(v);
  out[(size_t)n * 256 + k] = hi;
  out[(size_t)n * 256 + 128 + k] = f2bf(v - bf2f(hi));
}

// ---- bf16 GEMM: C[m][n] = sum_k A[m][k] * B[n][k]  (B^T layout), f32 out ----
// 128x128 tile, BK=64, 4 waves (2x2), 16x16x32 MFMA, global_load_lds width 16.
// + split-K (partials at C + s*cstride), T2 XOR-swizzled LDS (both-sides),
// + bijective XCD-chunk block mapping with (s, tm, tn) order (tn fastest).
__global__ __launch_bounds__(256) void gemm_bt(
    const u16* __restrict__ A, int lda,
    const u16* __restrict__ B, int ldb,
    float* __restrict__ C, int ldc, size_t cstride,
    const float* __restrict__ bias,
    int M, int N, int kchunk, int Ktot,
    int ntm, int ntn) {
  __shared__ __align__(16) u16 lA[128 * 64];
  __shared__ __align__(16) u16 lB[128 * 64];
  const int tid = threadIdx.x;
  const int w = tid >> 6, l = tid & 63;

  // bijective XCD chunking (m204): consecutive virtual ids land on one XCD
  const int nb = gridDim.x;
  const int bid = blockIdx.x;
  const int q = nb >> 3, r = nb & 7;
  const int xcd = bid & 7, ii = bid >> 3;
  const int v = (xcd < r ? xcd * (q + 1) : r * (q + 1) + (xcd - r) * q) + ii;
  const int per = ntm * ntn;
  const int s = v / per;
  const int rem = v - s * per;
  const int tm = rem / ntn, tn = rem - tm * ntn;
  const int kb = s * kchunk;
  const int ke = (kb + kchunk < Ktot) ? kb + kchunk : Ktot;
  float* Cb = C + (size_t)s * cstride;

  const u16* Ab = A + (size_t)tm * 128 * lda;
  const u16* Bb = B + (size_t)tn * 128 * ldb;
  f32x4 acc[4][4];
#pragma unroll
  for (int i = 0; i < 4; ++i)
#pragma unroll
    for (int j = 0; j < 4; ++j) acc[i][j] = (f32x4){0.f, 0.f, 0.f, 0.f};

  const int wm = w >> 1, wn = w & 1;
  const int arow = wm * 64 + (l & 15);
  const int brow = wn * 64 + (l & 15);
  // swizzled ds_read chunk offsets (chunk ^= row&7; row&7 == l&7 here)
  const int kx0 = ((((l >> 4)) ^ (l & 7)) << 3);
  const int kx1 = (((4 + (l >> 4)) ^ (l & 7)) << 3);
  // staging: pre-swizzled global source column (rule #21: linear LDS dest)
  const int srow = w * 8 + (l >> 3);
  const int scol = (((l & 7) ^ ((l >> 3) & 7)) << 3);

  for (int k0 = kb; k0 < ke; k0 += 64) {
#pragma unroll
    for (int i = 0; i < 4; ++i) {
      gload_lds16(Ab + (size_t)(srow + i * 32) * lda + k0 + scol, &lA[(i * 256 + w * 64) * 8]);
      gload_lds16(Bb + (size_t)(srow + i * 32) * ldb + k0 + scol, &lB[(i * 256 + w * 64) * 8]);
    }
    __syncthreads();
#pragma unroll
    for (int kk = 0; kk < 2; ++kk) {
      const int kx = kk ? kx1 : kx0;
      bf16x8 af[4], bb[4];
#pragma unroll
      for (int mi = 0; mi < 4; ++mi)
        af[mi] = *(const bf16x8*)&lA[(arow + mi * 16) * 64 + kx];
#pragma unroll
      for (int ni = 0; ni < 4; ++ni)
        bb[ni] = *(const bf16x8*)&lB[(brow + ni * 16) * 64 + kx];
#pragma unroll
      for (int mi = 0; mi < 4; ++mi)
#pragma unroll
        for (int ni = 0; ni < 4; ++ni)
          acc[mi][ni] = __builtin_amdgcn_mfma_f32_16x16x32_bf16(af[mi], bb[ni], acc[mi][ni], 0, 0, 0);
    }
    __syncthreads();
  }
  const int crow = wm * 64 + ((l >> 4) << 2);
  const int ccol = wn * 64 + (l & 15);
#pragma unroll
  for (int mi = 0; mi < 4; ++mi) {
#pragma unroll
    for (int j = 0; j < 4; ++j) {
      int grow = tm * 128 + crow + mi * 16 + j;
      if (grow < M) {
#pragma unroll
        for (int ni = 0; ni < 4; ++ni) {
          int gcol = tn * 128 + ccol + ni * 16;
          if (gcol < N) {
            float vv = acc[mi][ni][j];
            if (bias) vv += bias[gcol];
            Cb[(size_t)grow * ldc + gcol] = vv;
          }
        }
      }
    }
  }
}

static inline int imin(int a, int b) { return a < b ? a : b; }

extern "C" void kernel_launch(void* const* d_in, const int* in_sizes, int n_in,
                              void* d_out, int out_size, void* d_ws, size_t ws_size,
                              hipStream_t stream) {
  const float* signal = (const float*)d_in[0];
  const int*   bc_idx = (const int*)d_in[1];
  const float* bc_w   = (const float*)d_in[2];
  const float* tmpl[3] = { (const float*)d_in[3], (const float*)d_in[5], (const float*)d_in[7] };
  const float* tb[3]   = { (const float*)d_in[4], (const float*)d_in[6], (const float*)d_in[8] };
  const float* Wd = (const float*)d_in[9];
  const float* bd = (const float*)d_in[10];
  float* outp = (float*)d_out;

  char* ws = (char*)d_ws;
  size_t off = 0;
  auto alloc = [&](size_t b) -> void* {
    size_t o = (off + 255) & ~(size_t)255; off = o + b; return (void*)(ws + o);
  };
  u16* sigbf = (u16*)alloc((size_t)V_N * 544 * 2);
  u16* outL0 = (u16*)alloc((size_t)V_PAD * 96 * 2);
  u16* outL1 = (u16*)alloc((size_t)V_PAD * 128 * 2);
  u16* outL2 = (u16*)alloc((size_t)V_PAD * 256 * 2);   // split hi|lo
  u16* trot  = (u16*)alloc((size_t)768 * 21760 * 2);   // max over layers; reused for WdT
  float* gemmC = (float*)alloc((size_t)4 * V_PAD * 768 * 4); // split-K partials (85MB covers all layers)
  size_t o2 = (off + 255) & ~(size_t)255;
  u16* interp = (u16*)(ws + o2);
  size_t interpElems = (ws_size > o2) ? (ws_size - o2) / 2 : 0;

  { // signal -> bf16
    int total4 = V_N * 544 / 4;
    cvt_kernel<<<dim3((total4 + 255) / 256), dim3(256), 0, stream>>>(signal, sigbf, total4);
  }

  const int TnA[3] = {96, 128, 128}, CcA[3] = {544, 96, 128};
  const int SplitA[3] = {4, 2, 2};
  u16* outs[3] = { outL0, outL1, outL2 };
  const u16* cursig = sigbf;
  for (int L = 0; L < 3; ++L) {
    const int Tn = TnA[L], Cc = CcA[L];
    const int K = 40 * Cc, N = 8 * Tn, C8 = Cc / 8, C4 = Cc / 4;
    const int nsplit = SplitA[L];
    const int kchunk = K / nsplit;           // all multiples of 64
    const size_t cstride = (size_t)V_PAD * N;
    { int total = N * 40 * C4;
      trot_kernel<<<dim3((total + 255) / 256), dim3(256), 0, stream>>>(tmpl[L], trot, Tn, Cc, C4, total); }
    long crl = (long)(interpElems / (size_t)K) & ~(long)127;
    int cr = (crl > (long)V_PAD) ? V_PAD : (int)crl;
    if (cr < 128) cr = 128;  // requires ws_size >= fixed(~135MB) + 5.6MB
    for (int v0 = 0; v0 < V_PAD; v0 += cr) {
      int rows = imin(cr, V_PAD - v0);
      int nv = imin(rows, V_N - v0);
      { int total = nv * 40 * C8;
        interp_kernel<<<dim3((total + 255) / 256), dim3(256), 0, stream>>>(
            cursig, Cc, C8, bc_idx, bc_w, interp, v0, K, total); }
      int ntm = rows / 128, ntn = N / 128;
      gemm_bt<<<dim3(ntm * ntn * nsplit), dim3(256), 0, stream>>>(
          interp, K, trot, K, gemmC + (size_t)v0 * N, N, cstride, nullptr, nv, N, kchunk, K, ntm, ntn);
    }
    { int total = V_N * Tn;
      int ldo = (L == 2) ? 256 : ((L == 0) ? 96 : 128);
      amp_kernel<<<dim3((total + 255) / 256), dim3(256), 0, stream>>>(
          gemmC, cstride, nsplit, tb[L], outs[L], Tn, ldo, (L == 2) ? 1 : 0, total); }
    cursig = outs[L];
  }

  { int total = V_PAD * 128;
    wdt_kernel<<<dim3((total + 255) / 256), dim3(256), 0, stream>>>(Wd, trot, total); }
  gemm_bt<<<dim3(54 * 54), dim3(256), 0, stream>>>(
      outL2, 256, trot, 256, outp, V_N, 0, bd, V_N, V_N, 256, 256, 54, 54);
}

// Round 3
// 757.465 us; speedup vs baseline: 1.4886x; 1.2476x over previous
//
#include <hip/hip_runtime.h>

typedef unsigned short u16;
typedef unsigned int   u32;
typedef __bf16 bf16x8 __attribute__((ext_vector_type(8)));
typedef float  f32x4  __attribute__((ext_vector_type(4)));
typedef u32    u32x4  __attribute__((ext_vector_type(4)));
typedef u16    u16x4  __attribute__((ext_vector_type(4)));

#define V_N   6890
#define V_PAD 6912

__device__ __forceinline__ float bf2f(u32 h) {
  union { u32 u; float f; } c; c.u = h << 16; return c.f;
}
__device__ __forceinline__ u16 f2bf(float f) {
  union { float f; u32 u; } c; c.f = f;
  return (u16)((c.u + 0x7fffu + ((c.u >> 16) & 1u)) >> 16);
}
__device__ __forceinline__ void gload_lds16(const void* g, void* l) {
  __builtin_amdgcn_global_load_lds((const __attribute__((address_space(1))) void*)g,
                                   (__attribute__((address_space(3))) void*)l, 16, 0, 0);
}

// ---- f32 -> bf16 (vec4) ----
__global__ void cvt_kernel(const float* __restrict__ in, u16* __restrict__ out, int total4) {
  int g = blockIdx.x * 256 + threadIdx.x;
  if (g >= total4) return;
  f32x4 v = *(const f32x4*)(in + (size_t)g * 4);
  u16x4 o; o.x = f2bf(v.x); o.y = f2bf(v.y); o.z = f2bf(v.z); o.w = f2bf(v.w);
  *(u16x4*)(out + (size_t)g * 4) = o;
}

// ---- build rotated templates, bf16, B^T layout ----
__global__ void trot_kernel(const float* __restrict__ T, u16* __restrict__ out,
                            int Tn, int Cc, int C4, int total) {
  int g = blockIdx.x * 256 + threadIdx.x;
  if (g >= total) return;
  int c4 = g % C4; int q = g / C4;
  int a = q & 7; q >>= 3;
  int r = q % 5; q /= 5;
  int t = q % Tn; int o = q / Tn;
  f32x4 s = *(const f32x4*)(T + (size_t)((t * 5 + r) * 8 + ((a - o + 8) & 7)) * Cc + c4 * 4);
  u16x4 d; d.x = f2bf(s.x); d.y = f2bf(s.y); d.z = f2bf(s.z); d.w = f2bf(s.w);
  *(u16x4*)(out + ((size_t)(o * Tn + t) * 40 + (r * 8 + a)) * Cc + c4 * 4) = d;
}

// ---- barycentric gather+interp ----
__global__ void interp_kernel(const u16* __restrict__ sig, int Cc, int C8,
                              const int* __restrict__ idx, const float* __restrict__ w,
                              u16* __restrict__ out, int v0, int Kl, int total) {
  int g = blockIdx.x * 256 + threadIdx.x;
  if (g >= total) return;
  int q = g / C8, c8 = g - q * C8;
  int vr = q / 40, ra = q - vr * 40;
  size_t ib = ((size_t)(v0 + vr) * 40 + ra) * 3;
  int i0 = idx[ib], i1 = idx[ib + 1], i2 = idx[ib + 2];
  float w0 = w[ib], w1 = w[ib + 1], w2 = w[ib + 2];
  u32x4 s0 = *(const u32x4*)(sig + (size_t)i0 * Cc + c8 * 8);
  u32x4 s1 = *(const u32x4*)(sig + (size_t)i1 * Cc + c8 * 8);
  u32x4 s2 = *(const u32x4*)(sig + (size_t)i2 * Cc + c8 * 8);
  u32x4 o;
#pragma unroll
  for (int j = 0; j < 4; ++j) {
    float lo = w0 * bf2f(s0[j] & 0xffffu) + w1 * bf2f(s1[j] & 0xffffu) + w2 * bf2f(s2[j] & 0xffffu);
    float hi = w0 * bf2f(s0[j] >> 16)     + w1 * bf2f(s1[j] >> 16)     + w2 * bf2f(s2[j] >> 16);
    o[j] = (u32)f2bf(lo) | ((u32)f2bf(hi) << 16);
  }
  *(u32x4*)(out + (size_t)vr * Kl + ra * Cc + c8 * 8) = o;
}

// ---- split-K reduce + relu(+bias) + angular max; optional split-bf16 (hi|lo) output ----
__global__ void amp_kernel(const float* __restrict__ Cin, size_t cstride, int nsplit,
                           const float* __restrict__ bias, u16* __restrict__ out,
                           int Tn, int ldo, int split, int total) {
  int g = blockIdx.x * 256 + threadIdx.x;
  if (g >= total) return;
  int t = g % Tn, v = g / Tn;
  const float* row = Cin + (size_t)v * (8 * Tn) + t;
  float acc[8];
#pragma unroll
  for (int o = 0; o < 8; ++o) acc[o] = row[(size_t)o * Tn];
  for (int s = 1; s < nsplit; ++s) {
    row += cstride;
#pragma unroll
    for (int o = 0; o < 8; ++o) acc[o] += row[(size_t)o * Tn];
  }
  float b = bias[t];
  float m = acc[0] + b;
#pragma unroll
  for (int o = 1; o < 8; ++o) m = fmaxf(m, acc[o] + b);
  m = fmaxf(m, 0.f);
  u16 hi = f2bf(m);
  out[(size_t)v * ldo + t] = hi;
  if (split) out[(size_t)v * ldo + Tn + t] = f2bf(m - bf2f(hi));
}

// ---- Wd [128][V] f32 -> WdT split-bf16 [V_PAD][256] (hi | lo along k) ----
__global__ void wdt_kernel(const float* __restrict__ Wd, u16* __restrict__ out, int total) {
  int g = blockIdx.x * 256 + threadIdx.x;
  if (g >= total) return;
  int k = g & 127, n = g >> 7;
  float v = (n < V_N) ? Wd[(size_t)k * V_N + n] : 0.f;
  u16 hi = f2bf(v);
  out[(size_t)n * 256 + k] = hi;
  out[(size_t)n * 256 + 128 + k] = f2bf(v - bf2f(hi));
}

// ---- 256x256 bf16 GEMM, BK=64, 8 waves (2Mx4N), double-buffered LDS (128 KiB),
//      counted vmcnt(8) prefetch (T3+T4), T2 XOR swizzle, T5 setprio,
//      split-K partials, bijective XCD block mapping. C = A * B^T (+bias). ----
__global__ __launch_bounds__(512, 2) void gemm256(
    const u16* __restrict__ A, int lda,
    const u16* __restrict__ B, int ldb,
    float* __restrict__ C, int ldc, size_t cstride,
    const float* __restrict__ bias,
    int Mvalid, int Nvalid, int kchunk, int Ktot,
    int ntm, int ntn) {
  __shared__ __align__(16) u16 lA[2][256 * 64];
  __shared__ __align__(16) u16 lB[2][256 * 64];
  const int tid = threadIdx.x;
  const int w = tid >> 6, l = tid & 63;

  // bijective XCD chunking (m204)
  const int nb = gridDim.x, bid = blockIdx.x;
  const int q = nb >> 3, r = nb & 7;
  const int xcd = bid & 7, ii = bid >> 3;
  const int v = (xcd < r ? xcd * (q + 1) : r * (q + 1) + (xcd - r) * q) + ii;
  const int per = ntm * ntn;
  const int s = v / per;
  const int rem = v - s * per;
  const int tm = rem / ntn, tn = rem - tm * ntn;
  const int kb = s * kchunk;
  int ke = kb + kchunk; if (ke > Ktot) ke = Ktot;
  const int nt = (ke - kb + 63) >> 6;
  float* Cb = C + (size_t)s * cstride;

  const u16* Ab = A + (size_t)(tm * 256) * lda + kb;
  const u16* Bb = B + (size_t)(tn * 256) * ldb + kb;

  // staging addressing (pre-swizzled global source, linear LDS dest; rule #21)
  const int srow = tid >> 3;                                  // 0..63 (+i*64)
  const int scol = (((l & 7) ^ (srow & 7)) << 3);             // elements
  u16* laBase = &lA[0][0];
  u16* lbBase = &lB[0][0];

  auto STAGE = [&](int buf, int k0) {
    const u16* ga = Ab + (size_t)srow * lda + k0 + scol;
    const u16* gb = Bb + (size_t)srow * ldb + k0 + scol;
    u16* la = laBase + buf * (256 * 64) + w * 512;
    u16* lb = lbBase + buf * (256 * 64) + w * 512;
#pragma unroll
    for (int i = 0; i < 4; ++i) {
      gload_lds16(ga + (size_t)(i * 64) * lda, la + i * 4096);
      gload_lds16(gb + (size_t)(i * 64) * ldb, lb + i * 4096);
    }
  };

  f32x4 acc[8][4];
#pragma unroll
  for (int i = 0; i < 8; ++i)
#pragma unroll
    for (int j = 0; j < 4; ++j) acc[i][j] = (f32x4){0.f, 0.f, 0.f, 0.f};

  const int wm = w >> 2, wn = w & 3;
  const int aoffbase = (wm * 128 + (l & 15)) * 64;
  const int boffbase = (wn * 64 + (l & 15)) * 64;
  const int swz = l & 7;
  const int ksel = l >> 4;  // 0..3

  STAGE(0, 0);
  int cur = 0;
  for (int t = 0; t < nt; ++t) {
    if (t + 1 < nt) STAGE(cur ^ 1, (t + 1) * 64);
    __builtin_amdgcn_sched_barrier(0);
    if (t + 1 < nt) { asm volatile("s_waitcnt vmcnt(8)" ::: "memory"); }
    else            { asm volatile("s_waitcnt vmcnt(0)" ::: "memory"); }
    __builtin_amdgcn_s_barrier();
    __builtin_amdgcn_sched_barrier(0);
    const u16* lab = laBase + cur * (256 * 64);
    const u16* lbb = lbBase + cur * (256 * 64);
#pragma unroll
    for (int kk = 0; kk < 2; ++kk) {
      const int kc = (((kk * 4 + ksel) ^ swz) << 3);
      bf16x8 bfr[4];
#pragma unroll
      for (int ni = 0; ni < 4; ++ni)
        bfr[ni] = *(const bf16x8*)&lbb[boffbase + ni * 1024 + kc];
#pragma unroll
      for (int mh = 0; mh < 2; ++mh) {
        bf16x8 afr[4];
#pragma unroll
        for (int mi = 0; mi < 4; ++mi)
          afr[mi] = *(const bf16x8*)&lab[aoffbase + (mh * 4 + mi) * 1024 + kc];
        __builtin_amdgcn_s_setprio(1);
#pragma unroll
        for (int mi = 0; mi < 4; ++mi)
#pragma unroll
          for (int ni = 0; ni < 4; ++ni)
            acc[mh * 4 + mi][ni] =
                __builtin_amdgcn_mfma_f32_16x16x32_bf16(afr[mi], bfr[ni], acc[mh * 4 + mi][ni], 0, 0, 0);
        __builtin_amdgcn_s_setprio(0);
      }
    }
    __builtin_amdgcn_sched_barrier(0);
    __builtin_amdgcn_s_barrier();
    cur ^= 1;
  }

  const int row0 = tm * 256 + wm * 128 + ((l >> 4) << 2);
  const int col0 = tn * 256 + wn * 64 + (l & 15);
#pragma unroll
  for (int mi = 0; mi < 8; ++mi) {
#pragma unroll
    for (int j = 0; j < 4; ++j) {
      int grow = row0 + mi * 16 + j;
      if (grow < Mvalid) {
#pragma unroll
        for (int ni = 0; ni < 4; ++ni) {
          int gcol = col0 + ni * 16;
          if (gcol < Nvalid) {
            float vv = acc[mi][ni][j];
            if (bias) vv += bias[gcol];
            Cb[(size_t)grow * ldc + gcol] = vv;
          }
        }
      }
    }
  }
}

static inline int imin(int a, int b) { return a < b ? a : b; }

extern "C" void kernel_launch(void* const* d_in, const int* in_sizes, int n_in,
                              void* d_out, int out_size, void* d_ws, size_t ws_size,
                              hipStream_t stream) {
  const float* signal = (const float*)d_in[0];
  const int*   bc_idx = (const int*)d_in[1];
  const float* bc_w   = (const float*)d_in[2];
  const float* tmpl[3] = { (const float*)d_in[3], (const float*)d_in[5], (const float*)d_in[7] };
  const float* tb[3]   = { (const float*)d_in[4], (const float*)d_in[6], (const float*)d_in[8] };
  const float* Wd = (const float*)d_in[9];
  const float* bd = (const float*)d_in[10];
  float* outp = (float*)d_out;

  char* ws = (char*)d_ws;
  size_t off = 0;
  auto alloc = [&](size_t b) -> void* {
    size_t o = (off + 255) & ~(size_t)255; off = o + b; return (void*)(ws + o);
  };
  u16* sigbf = (u16*)alloc((size_t)V_N * 544 * 2);
  u16* outL0 = (u16*)alloc((size_t)V_PAD * 96 * 2);
  u16* outL1 = (u16*)alloc((size_t)V_PAD * 128 * 2);
  u16* outL2 = (u16*)alloc((size_t)V_PAD * 256 * 2);      // split hi|lo
  u16* trot  = (u16*)alloc((size_t)1024 * 21760 * 2);     // max over layers; reused for WdT
  float* gemmC = (float*)alloc((size_t)6 * V_PAD * 768 * 4); // split-K partials (127 MB max)
  size_t o2 = (off + 255) & ~(size_t)255;
  u16* interp = (u16*)(ws + o2);
  size_t interpElems = (ws_size > o2) ? (ws_size - o2) / 2 : 0;

  { int total4 = V_N * 544 / 4;
    cvt_kernel<<<dim3((total4 + 255) / 256), dim3(256), 0, stream>>>(signal, sigbf, total4); }

  const int TnA[3] = {96, 128, 128}, CcA[3] = {544, 96, 128};
  const int SplitA[3] = {6, 4, 4};
  const int CrA[3] = {3584, V_PAD, V_PAD};   // L0 M-chunks sized for ~1 block/CU rounds
  u16* outs[3] = { outL0, outL1, outL2 };
  const u16* cursig = sigbf;
  for (int L = 0; L < 3; ++L) {
    const int Tn = TnA[L], Cc = CcA[L];
    const int K = 40 * Cc, N = 8 * Tn, C8 = Cc / 8, C4 = Cc / 4;
    const int nsplit = SplitA[L];
    const int kchunk = ((K / 64 + nsplit - 1) / nsplit) * 64;  // multiple of 64
    const size_t cstride = (size_t)V_PAD * N;
    { int total = N * 40 * C4;
      trot_kernel<<<dim3((total + 255) / 256), dim3(256), 0, stream>>>(tmpl[L], trot, Tn, Cc, C4, total); }
    long crl = (long)(interpElems / (size_t)K) & ~(long)255;
    int cr = (crl > (long)CrA[L]) ? CrA[L] : (int)crl;
    if (cr < 256) cr = 256;  // needs ws_size >= fixed(~175MB) + 11MB
    const int ntn = N / 256;
    for (int v0 = 0; v0 < V_PAD; v0 += cr) {
      int rows = imin(cr, V_PAD - v0);
      int nv = imin(rows, V_N - v0);
      { int total = nv * 40 * C8;
        interp_kernel<<<dim3((total + 255) / 256), dim3(256), 0, stream>>>(
            cursig, Cc, C8, bc_idx, bc_w, interp, v0, K, total); }
      int ntm = rows / 256;
      gemm256<<<dim3(ntm * ntn * nsplit), dim3(512), 0, stream>>>(
          interp, K, trot, K, gemmC + (size_t)v0 * N, N, cstride, nullptr, nv, N, kchunk, K, ntm, ntn);
    }
    { int total = V_N * Tn;
      int ldo = (L == 2) ? 256 : ((L == 0) ? 96 : 128);
      amp_kernel<<<dim3((total + 255) / 256), dim3(256), 0, stream>>>(
          gemmC, cstride, nsplit, tb[L], outs[L], Tn, ldo, (L == 2) ? 1 : 0, total); }
    cursig = outs[L];
  }

  { int total = V_PAD * 128;
    wdt_kernel<<<dim3((total + 255) / 256), dim3(256), 0, stream>>>(Wd, trot, total); }
  gemm256<<<dim3(27 * 27), dim3(512), 0, stream>>>(
      outL2, 256, trot, 256, outp, V_N, 0, bd, V_N, V_N, 256, 256, 27, 27);
}